// Round 9
// baseline (250.590 us; speedup 1.0000x reference)
//
#include <hip/hip_runtime.h>
#include <hip/hip_bf16.h>

#define BB 8
#define TT 1024
#define FF 512
#define DD 64
#define LCH 16
#define CCH (TT / LCH)

__device__ __forceinline__ float wave_sum64(float v) {
  #pragma unroll
  for (int m = 32; m >= 1; m >>= 1) v += __shfl_xor(v, m, 64);
  return v;
}

// ---------------- Kernel 1: LayerNorm, writes xn (fp32) ----------
__global__ __launch_bounds__(256) void ln_k(const float* __restrict__ x,
                                            const float* __restrict__ gamma,
                                            const float* __restrict__ beta,
                                            float* __restrict__ xn) {
  int wv = threadIdx.x >> 6, lane = threadIdx.x & 63;
  int row = blockIdx.x * 4 + wv;
  const float* xr = x + (size_t)row * FF;
  float v[8];
  float s = 0.f, ss = 0.f;
  #pragma unroll
  for (int k = 0; k < 8; ++k) {
    v[k] = xr[lane + 64 * k];
    s += v[k]; ss += v[k] * v[k];
  }
  s = wave_sum64(s); ss = wave_sum64(ss);
  float m = s * (1.f / FF);
  float var = ss * (1.f / FF) - m * m;
  float r = rsqrtf(var + 1e-5f);
  float* xo = xn + (size_t)row * FF;
  #pragma unroll
  for (int k = 0; k < 8; ++k) {
    int f = lane + 64 * k;
    xo[f] = (v[k] - m) * r * gamma[f] + beta[f];
  }
}

// ---------------- Kernel 2: projection (+relu+sumnorm) ------------------
__global__ __launch_bounds__(64) void proj_k(const float* __restrict__ xn,
                      const float* __restrict__ Wk, const float* __restrict__ Wq,
                      const float* __restrict__ Wv,
                      float* __restrict__ Ko, float* __restrict__ Qo,
                      float* __restrict__ Vo) {
  int bx = blockIdx.x;
  int p = bx >> 10;            // 0=K,1=Q,2=V (uniform per block)
  int row0 = (bx & 1023) * 8;
  int lane = threadIdx.x;      // = d
  const float* Wp = (p == 0) ? Wk : (p == 1) ? Wq : Wv;
  float* outp = (p == 0) ? Ko : (p == 1) ? Qo : Vo;
  float acc[8] = {0.f,0.f,0.f,0.f,0.f,0.f,0.f,0.f};
  const float* xr = xn + (size_t)row0 * FF;
  for (int f = 0; f < FF; f += 4) {
    float w0 = Wp[(f + 0) * DD + lane];   // coalesced, L2-resident
    float w1 = Wp[(f + 1) * DD + lane];
    float w2 = Wp[(f + 2) * DD + lane];
    float w3 = Wp[(f + 3) * DD + lane];
    #pragma unroll
    for (int r = 0; r < 8; ++r) {
      float4 xv = *(const float4*)(xr + (size_t)r * FF + f);  // wave-uniform
      acc[r] += (xv.x * w0 + xv.y * w1) + (xv.z * w2 + xv.w * w3);
    }
  }
  #pragma unroll
  for (int r = 0; r < 8; ++r) {
    int row = row0 + r;
    float val = acc[r];
    if (p < 2) {
      val = fmaxf(val, 0.f);
      float ssum = wave_sum64(val);
      val = val / (1e-5f + ssum);
    }
    outp[(size_t)row * DD + lane] = val;
  }
}

// ---------------- Kernel 3: per-chunk outer-product sums ----------------
__global__ __launch_bounds__(256) void chunksum_k(const float* __restrict__ Kx,
                                                  const float* __restrict__ Vx,
                                                  float* __restrict__ S) {
  int bc = blockIdx.x, tid = threadIdx.x;
  __shared__ float lk[LCH * DD], lv[LCH * DD];
  for (int e = tid; e < LCH * DD; e += 256) {
    lk[e] = Kx[(size_t)bc * LCH * DD + e];
    lv[e] = Vx[(size_t)bc * LCH * DD + e];
  }
  __syncthreads();
  int j = tid & 63, i0 = (tid >> 6) << 4;
  float acc[16];
  #pragma unroll
  for (int ii = 0; ii < 16; ++ii) acc[ii] = 0.f;
  for (int t = 0; t < LCH; ++t) {
    float kj = lk[t * DD + j];
    #pragma unroll
    for (int ii = 0; ii < 16; ++ii) acc[ii] += lv[t * DD + i0 + ii] * kj;
  }
  float* Sp = S + (size_t)bc * (DD * DD);
  #pragma unroll
  for (int ii = 0; ii < 16; ++ii) Sp[(i0 + ii) * DD + j] = acc[ii];
}

// ---------------- Kernel 4: exclusive prefix over chunks ----------------
__global__ __launch_bounds__(256) void prefix_k(const float* __restrict__ S,
                                                const float* __restrict__ st0,
                                                float* __restrict__ P) {
  int b = blockIdx.x >> 4;
  int e = ((blockIdx.x & 15) << 8) + threadIdx.x;
  float run = st0[(size_t)b * (DD * DD) + e];
  const float* Sb = S + ((size_t)b * CCH) * (DD * DD) + e;
  float* Pb = P + ((size_t)b * CCH) * (DD * DD) + e;
  for (int c = 0; c < CCH; ++c) {
    Pb[(size_t)c * (DD * DD)] = run;
    run += Sb[(size_t)c * (DD * DD)];
  }
}

// ---------------- Kernel 5: in-chunk scan + y (fp32 outputs!) ----------
__global__ __launch_bounds__(64) void scan_k(const float* __restrict__ Kx,
                     const float* __restrict__ Qx, const float* __restrict__ Vx,
                     const float* __restrict__ P,
                     float* __restrict__ y, float* __restrict__ sout) {
  int bc = blockIdx.x, j = threadIdx.x;
  float S[DD];
  const float* Pp = P + (size_t)bc * (DD * DD);
  #pragma unroll
  for (int i = 0; i < DD; ++i) S[i] = Pp[i * DD + j];
  const float* Kb = Kx + (size_t)bc * LCH * DD;
  const float* Vb = Vx + (size_t)bc * LCH * DD;
  const float* Qb = Qx + (size_t)bc * LCH * DD;
  float kreg[LCH];
  #pragma unroll
  for (int t = 0; t < LCH; ++t) kreg[t] = Kb[t * DD + j];
  float* so = sout + (size_t)bc * LCH * (DD * DD) + j;
  float* yo = y + (size_t)bc * LCH * DD + j;
  for (int t = 0; t < LCH; ++t) {
    const float* Vt = Vb + t * DD;   // wave-uniform -> scalar loads
    const float* Qt = Qb + t * DD;
    float kj = kreg[t];
    float y0 = 0.f, y1 = 0.f, y2 = 0.f, y3 = 0.f;
    float* sot = so + (size_t)t * (DD * DD);
    #pragma unroll
    for (int i = 0; i < DD; i += 4) {
      S[i]     += Vt[i]     * kj; sot[(i)     * DD] = S[i];     y0 += S[i]     * Qt[i];
      S[i + 1] += Vt[i + 1] * kj; sot[(i + 1) * DD] = S[i + 1]; y1 += S[i + 1] * Qt[i + 1];
      S[i + 2] += Vt[i + 2] * kj; sot[(i + 2) * DD] = S[i + 2]; y2 += S[i + 2] * Qt[i + 2];
      S[i + 3] += Vt[i + 3] * kj; sot[(i + 3) * DD] = S[i + 3]; y3 += S[i + 3] * Qt[i + 3];
    }
    yo[t * DD] = (y0 + y1) + (y2 + y3);
  }
}

extern "C" void kernel_launch(void* const* d_in, const int* in_sizes, int n_in,
                              void* d_out, int out_size, void* d_ws, size_t ws_size,
                              hipStream_t stream) {
  const float* x     = (const float*)d_in[0];
  const float* st0   = (const float*)d_in[1];
  const float* Wk    = (const float*)d_in[2];
  const float* Wq    = (const float*)d_in[3];
  const float* Wv    = (const float*)d_in[4];
  const float* gamma = (const float*)d_in[5];
  const float* beta  = (const float*)d_in[6];

  float* out  = (float*)d_out;                    // fp32 — reference dtype!
  float* yout = out;                              // y [B,T,D] first
  float* sseq = out + (size_t)BB * TT * DD;       // state_seq [B,T,D,D]

  float* ws = (float*)d_ws;
  float* xn = ws;
  float* Ko = xn + (size_t)BB * TT * FF;
  float* Qo = Ko + (size_t)BB * TT * DD;
  float* Vo = Qo + (size_t)BB * TT * DD;
  float* S  = Vo + (size_t)BB * TT * DD;
  float* P  = S  + (size_t)BB * CCH * DD * DD;

  ln_k      <<<BB * TT / 4, 256, 0, stream>>>(x, gamma, beta, xn);
  proj_k    <<<3 * BB * TT / 8, 64, 0, stream>>>(xn, Wk, Wq, Wv, Ko, Qo, Vo);
  chunksum_k<<<BB * CCH, 256, 0, stream>>>(Ko, Vo, S);
  prefix_k  <<<BB * 16, 256, 0, stream>>>(S, st0, P);
  scan_k    <<<BB * CCH, 64, 0, stream>>>(Ko, Qo, Vo, P, yout, sseq);
}